// Round 1
// baseline (39.639 us; speedup 1.0000x reference)
//
#include <hip/hip_runtime.h>
#include <math.h>

#define BB 2048   // batch B
#define NN 512    // classes N
#define DD 256    // dim D

#define BM 64
#define BN 64
#define BK 32

__device__ __forceinline__ float blockReduceSum(float v, float* sbuf) {
    #pragma unroll
    for (int o = 32; o > 0; o >>= 1) v += __shfl_down(v, o, 64);
    __syncthreads();                       // protect sbuf from prior use
    if ((threadIdx.x & 63) == 0) sbuf[threadIdx.x >> 6] = v;
    __syncthreads();
    return sbuf[0] + sbuf[1] + sbuf[2] + sbuf[3];
}

// One block per row: rows [0,BB) transform x -> xb (Poincare), rows [BB, BB+NN)
// transform p/a. Writes transposed layouts for stage2.
__global__ __launch_bounds__(256) void hmlr_stage1(
    const float* __restrict__ x, const float* __restrict__ a_vals,
    const float* __restrict__ p_vals,
    float* __restrict__ xbT, float* __restrict__ ppT, float* __restrict__ apT,
    float* __restrict__ y2, float* __restrict__ p2s, float* __restrict__ pas,
    float* __restrict__ ans, float* __restrict__ ks)
{
    __shared__ float sbuf[4];
    const int t = threadIdx.x;       // = d index, DD == 256 == blockDim.x
    const int r = blockIdx.x;

    if (r < BB) {
        float v = x[r * DD + t];
        float ss = blockReduceSum(v * v, sbuf);
        float norm0 = sqrtf(ss);
        float x_norm = norm0 + 1e-5f;                 // ||x|| + 1e-5
        float fac = fminf(1.0f, 1.0f / x_norm);       // clip to CLIP_R=1
        float xc = v * fac;
        float xcn = norm0 * fac;                      // ||x*fac||
        float u_norm = fmaxf(xcn, 1e-5f);
        float th = tanhf(u_norm);                     // sqrt_c = 1
        float e = xc * (th / u_norm);                 // expmap0
        // project: norm = max(||e||,1e-5); clamp to 0.999 (never triggers here
        // since th < tanh(1) < 0.999, but implement faithfully)
        float en = fmaxf(th, 1e-5f);
        float w = (en > 0.999f) ? (0.999f / en) : 1.0f;
        float outv = e * w;
        xbT[(size_t)t * BB + r] = outv;
        if (t == 0) { float fn = th * w; y2[r] = fn * fn; }
    } else {
        int n = r - BB;
        float pv = p_vals[n * DD + t];
        float av = a_vals[n * DD + t];
        float ssp = blockReduceSum(pv * pv, sbuf);
        float pn0 = sqrtf(ssp);
        float u = fmaxf(pn0, 1e-5f);
        float th = tanhf(u);
        float s = th / u;
        float ppv = pv * s;                           // p_poincare
        float p2 = th * th;                           // ||pp||^2
        float conf = 1.0f - p2;                       // conformal factor
        float apv = av * conf;                        // a_poincare
        float ssa = blockReduceSum(av * av, sbuf);
        float an = sqrtf(ssa) * conf;                 // ||a_poincare|| (conf>0)
        float pa = blockReduceSum(ppv * apv, sbuf);   // P . A
        ppT[(size_t)t * NN + n] = ppv;
        apT[(size_t)t * NN + n] = apv;
        if (t == 0) {
            p2s[n] = p2;
            pas[n] = pa;
            ans[n] = an;
            ks[n] = (2.0f / conf) * an;               // lam * a_norm
        }
    }
}

// Tile (BM x BN) of output per block; dual fp32 GEMM (X.P^T and X.A^T) + fused
// hyperbolic-softmax epilogue. All operands pre-transposed: [k][col] staging.
__global__ __launch_bounds__(256) void hmlr_stage2(
    const float* __restrict__ xbT, const float* __restrict__ ppT,
    const float* __restrict__ apT, const float* __restrict__ y2,
    const float* __restrict__ p2s, const float* __restrict__ pas,
    const float* __restrict__ ans, const float* __restrict__ ks,
    float* __restrict__ out)
{
    __shared__ float Xs[BK][BM];
    __shared__ float Ps[BK][BN];
    __shared__ float As[BK][BN];

    const int t  = threadIdx.x;
    const int tx = t & 15;          // n direction
    const int ty = t >> 4;          // b direction
    const int n0 = blockIdx.x * BN;
    const int b0 = blockIdx.y * BM;

    float axy[4][4] = {{0.f}};      // sum X*P
    float axa[4][4] = {{0.f}};      // sum X*A

    for (int k0 = 0; k0 < DD; k0 += BK) {
        __syncthreads();
        #pragma unroll
        for (int rep = 0; rep < 2; ++rep) {
            int f4 = rep * 256 + t;            // 0..511 float4 slots
            int k  = f4 >> 4;                  // 0..31
            int c4 = (f4 & 15) << 2;           // 0..60
            float4 vx = *(const float4*)&xbT[(size_t)(k0 + k) * BB + b0 + c4];
            float4 vp = *(const float4*)&ppT[(size_t)(k0 + k) * NN + n0 + c4];
            float4 va = *(const float4*)&apT[(size_t)(k0 + k) * NN + n0 + c4];
            *(float4*)&Xs[k][c4] = vx;
            *(float4*)&Ps[k][c4] = vp;
            *(float4*)&As[k][c4] = va;
        }
        __syncthreads();
        #pragma unroll
        for (int k = 0; k < BK; ++k) {
            float4 xv = *(const float4*)&Xs[k][ty * 4];
            float4 pv = *(const float4*)&Ps[k][tx * 4];
            float4 av = *(const float4*)&As[k][tx * 4];
            const float* xf = (const float*)&xv;
            const float* pf = (const float*)&pv;
            const float* af = (const float*)&av;
            #pragma unroll
            for (int i = 0; i < 4; ++i) {
                #pragma unroll
                for (int j = 0; j < 4; ++j) {
                    axy[i][j] = fmaf(xf[i], pf[j], axy[i][j]);
                    axa[i][j] = fmaf(xf[i], af[j], axa[i][j]);
                }
            }
        }
    }

    // per-column (n) and per-row (b) scalars
    float p2v[4], pav[4], anv[4], kv[4], y2v[4];
    #pragma unroll
    for (int j = 0; j < 4; ++j) {
        int n = n0 + tx * 4 + j;
        p2v[j] = p2s[n]; pav[j] = pas[n]; anv[j] = ans[n]; kv[j] = ks[n];
    }
    #pragma unroll
    for (int i = 0; i < 4; ++i) y2v[i] = y2[b0 + ty * 4 + i];

    #pragma unroll
    for (int i = 0; i < 4; ++i) {
        float4 o;
        float* of = (float*)&o;
        #pragma unroll
        for (int j = 0; j < 4; ++j) {
            float xy  = -axy[i][j];                      // (-P).X
            float yy  = y2v[i];
            float p2  = p2v[j];
            float dnm = 1.f + 2.f * xy + p2 * yy + 1e-5f;
            float alpha = (1.f + 2.f * xy + yy) / dnm;   // coeff on (-P)
            float beta  = (1.f - p2) / dnm;              // coeff on X
            float num  = 2.f * (beta * axa[i][j] - alpha * pav[j]);
            float mob2 = alpha * alpha * p2 + beta * beta * yy
                       + 2.f * alpha * beta * xy;
            float den  = anv[j] * (1.f - mob2);
            of[j] = kv[j] * asinhf(num / den);
        }
        *(float4*)&out[(size_t)(b0 + ty * 4 + i) * NN + n0 + tx * 4] = o;
    }
}

extern "C" void kernel_launch(void* const* d_in, const int* in_sizes, int n_in,
                              void* d_out, int out_size, void* d_ws, size_t ws_size,
                              hipStream_t stream) {
    const float* x      = (const float*)d_in[0];
    const float* a_vals = (const float*)d_in[1];
    const float* p_vals = (const float*)d_in[2];
    float* out = (float*)d_out;

    float* ws  = (float*)d_ws;
    float* xbT = ws;                               // D*B
    float* ppT = xbT + (size_t)DD * BB;            // D*N
    float* apT = ppT + (size_t)DD * NN;            // D*N
    float* y2  = apT + (size_t)DD * NN;            // B
    float* p2s = y2 + BB;                          // N
    float* pas = p2s + NN;                         // N
    float* ans = pas + NN;                         // N
    float* ks  = ans + NN;                         // N

    hipLaunchKernelGGL(hmlr_stage1, dim3(BB + NN), dim3(256), 0, stream,
                       x, a_vals, p_vals, xbT, ppT, apT, y2, p2s, pas, ans, ks);
    hipLaunchKernelGGL(hmlr_stage2, dim3(NN / BN, BB / BM), dim3(256), 0, stream,
                       xbT, ppT, apT, y2, p2s, pas, ans, ks, out);
}

// Round 2
// 25.627 us; speedup vs baseline: 1.5467x; 1.5467x over previous
//
#include <hip/hip_runtime.h>
#include <math.h>

#define BB 2048   // batch B
#define NN 512    // classes N
#define DD 256    // dim D

typedef __attribute__((ext_vector_type(8))) short s16x8;   // 8 bf16 (4 VGPRs)
typedef __attribute__((ext_vector_type(4))) float f32x4;   // MFMA acc

__device__ __forceinline__ ushort f2bf(float f) {          // RNE float->bf16
    union { float f; unsigned u; } c; c.f = f;
    unsigned r = (c.u + 0x7fffu + ((c.u >> 16) & 1u)) >> 16;
    return (ushort)r;
}
__device__ __forceinline__ float bf2f(ushort h) {
    union { unsigned u; float f; } c; c.u = ((unsigned)h) << 16;
    return c.f;
}

__device__ __forceinline__ float blockReduceSum(float v, float* sbuf) {
    #pragma unroll
    for (int o = 32; o > 0; o >>= 1) v += __shfl_down(v, o, 64);
    __syncthreads();
    if ((threadIdx.x & 63) == 0) sbuf[threadIdx.x >> 6] = v;
    __syncthreads();
    return sbuf[0] + sbuf[1] + sbuf[2] + sbuf[3];
}

// Swizzled column index: within each 32-elem chunk, XOR bits 3..4 of the
// element index with ((row>>1)&3). In bytes: byte ^= ((row>>1)&3)<<4, which
// permutes 16B units inside each 64B chunk -> 16B alignment preserved.
__device__ __forceinline__ int swz_col(int d, int row) {
    return (d & ~31) | ((d & 31) ^ (((row >> 1) & 3) << 3));
}

// One block per row. Rows [0,BB): x -> Poincare ball, write bf16 hi/lo
// (swizzled). Rows [BB,BB+NN): p,a -> p_poincare / a_poincare + scalars.
__global__ __launch_bounds__(256) void hmlr_stage1(
    const float* __restrict__ x, const float* __restrict__ a_vals,
    const float* __restrict__ p_vals,
    ushort* __restrict__ Xh, ushort* __restrict__ Xl,
    ushort* __restrict__ Ph, ushort* __restrict__ Pl,
    ushort* __restrict__ Ah, ushort* __restrict__ Al,
    float* __restrict__ y2, float* __restrict__ p2s, float* __restrict__ pas,
    float* __restrict__ ans, float* __restrict__ ks)
{
    __shared__ float sbuf[4];
    const int t = threadIdx.x;       // = d index (DD == 256 == blockDim.x)
    const int r = blockIdx.x;

    if (r < BB) {
        float v = x[r * DD + t];
        float ss = blockReduceSum(v * v, sbuf);
        float norm0 = sqrtf(ss);
        float x_norm = norm0 + 1e-5f;
        float fac = fminf(1.0f, 1.0f / x_norm);       // CLIP_R = 1
        float xc = v * fac;
        float xcn = norm0 * fac;
        float u_norm = fmaxf(xcn, 1e-5f);
        float th = tanhf(u_norm);                     // sqrt_c = 1
        float e = xc * (th / u_norm);                 // expmap0
        float en = fmaxf(th, 1e-5f);
        float wgt = (en > 0.999f) ? (0.999f / en) : 1.0f;   // project
        float outv = e * wgt;
        int es = swz_col(t, r);
        ushort hi = f2bf(outv);
        ushort lo = f2bf(outv - bf2f(hi));
        Xh[r * DD + es] = hi;
        Xl[r * DD + es] = lo;
        if (t == 0) { float fn = th * wgt; y2[r] = fn * fn; }
    } else {
        int n = r - BB;
        float pv = p_vals[n * DD + t];
        float av = a_vals[n * DD + t];
        float ssp = blockReduceSum(pv * pv, sbuf);
        float pn0 = sqrtf(ssp);
        float u = fmaxf(pn0, 1e-5f);
        float th = tanhf(u);
        float s = th / u;
        float ppv = pv * s;                           // p_poincare
        float p2 = th * th;
        float conf = 1.0f - p2;                       // conformal
        float apv = av * conf;                        // a_poincare
        float ssa = blockReduceSum(av * av, sbuf);
        float an = sqrtf(ssa) * conf;
        float pa = blockReduceSum(ppv * apv, sbuf);
        int es = swz_col(t, n);
        ushort phi = f2bf(ppv);
        Ph[n * DD + es] = phi;
        Pl[n * DD + es] = f2bf(ppv - bf2f(phi));
        ushort ahi = f2bf(apv);
        Ah[n * DD + es] = ahi;
        Al[n * DD + es] = f2bf(apv - bf2f(ahi));
        if (t == 0) {
            p2s[n] = p2; pas[n] = pa; ans[n] = an;
            ks[n] = (2.0f / conf) * an;
        }
    }
}

// 64x64 output tile / block, grid (8,32) = 256 blocks = 1/CU.
// 4 waves, each a 32x32 quadrant = 2x2 fragments of mfma_f32_16x16x32_bf16.
// Dual GEMM (X.P^T and X.A^T) in split-bf16 (3 MFMA terms each).
// Double-buffered LDS, BK=32 per step, global_load_lds staging of
// pre-swizzled operands.
__global__ __launch_bounds__(256) void hmlr_stage2(
    const ushort* __restrict__ Xh, const ushort* __restrict__ Xl,
    const ushort* __restrict__ Ph, const ushort* __restrict__ Pl,
    const ushort* __restrict__ Ah, const ushort* __restrict__ Al,
    const float* __restrict__ y2, const float* __restrict__ p2s,
    const float* __restrict__ pas, const float* __restrict__ ans,
    const float* __restrict__ ks, float* __restrict__ out)
{
    __shared__ ushort lds[2][6][64][32];   // 48 KiB: Xh,Xl,Ph,Pl,Ah,Al tiles

    const int t    = threadIdx.x;
    const int lane = t & 63;
    const int w    = t >> 6;        // wave 0..3
    const int wr   = w >> 1;        // b-quadrant
    const int wc   = w & 1;         // n-quadrant
    const int n0   = blockIdx.x * 64;
    const int b0   = blockIdx.y * 64;

    const ushort* bases[6] = {Xh, Xl, Ph, Pl, Ah, Al};

    f32x4 axy[2][2], axa[2][2];
    #pragma unroll
    for (int m = 0; m < 2; ++m)
        #pragma unroll
        for (int n = 0; n < 2; ++n) {
            axy[m][n] = (f32x4){0.f, 0.f, 0.f, 0.f};
            axa[m][n] = (f32x4){0.f, 0.f, 0.f, 0.f};
        }

    // Stage one BK=32 column-slice of all 6 operand tiles into lds[buf].
    // Chunk assignment: iteration i stages tile i, row-group w (16 rows).
    // LDS dest is wave-uniform; HW adds lane*16B (linear), which matches
    // rows w*16+(lane>>2), bytes (lane&3)*16. Global source is the
    // pre-swizzled array, so a linear copy lands swizzled in LDS.
    auto stage = [&](int buf, int step) {
        #pragma unroll
        for (int i = 0; i < 6; ++i) {
            int grow = (i < 2 ? b0 : n0) + w * 16 + (lane >> 2);
            const ushort* g = bases[i] + (size_t)grow * DD + step * 32 + (lane & 3) * 8;
            const ushort* l = &lds[buf][i][w * 16][0];
            __builtin_amdgcn_global_load_lds(
                (const __attribute__((address_space(1))) unsigned int*)(const void*)g,
                (__attribute__((address_space(3))) unsigned int*)(void*)l,
                16, 0, 0);
        }
    };

    // Fragment read: lane supplies M[row=rbase+(lane&15)][k=(lane>>4)*8 .. +8]
    // (A and B operands use the same [row][k] addressing). Apply the swizzle.
    auto ldfrag = [&](int buf, int tile, int rbase) -> s16x8 {
        int row = rbase + (lane & 15);
        int byt = (((lane >> 4) ^ ((row >> 1) & 3)) << 4);
        return *(const s16x8*)((const char*)&lds[buf][tile][row][0] + byt);
    };

    stage(0, 0);
    for (int step = 0; step < 8; ++step) {
        __syncthreads();                       // drains vmcnt -> buf ready
        if (step < 7) stage((step + 1) & 1, step + 1);
        const int buf = step & 1;
        s16x8 xh[2], xl[2], ph[2], pl[2], ah[2], al[2];
        #pragma unroll
        for (int m = 0; m < 2; ++m) {
            xh[m] = ldfrag(buf, 0, wr * 32 + m * 16);
            xl[m] = ldfrag(buf, 1, wr * 32 + m * 16);
        }
        #pragma unroll
        for (int n = 0; n < 2; ++n) {
            ph[n] = ldfrag(buf, 2, wc * 32 + n * 16);
            pl[n] = ldfrag(buf, 3, wc * 32 + n * 16);
            ah[n] = ldfrag(buf, 4, wc * 32 + n * 16);
            al[n] = ldfrag(buf, 5, wc * 32 + n * 16);
        }
        #pragma unroll
        for (int m = 0; m < 2; ++m)
            #pragma unroll
            for (int n = 0; n < 2; ++n) {
                axy[m][n] = __builtin_amdgcn_mfma_f32_16x16x32_bf16(xh[m], ph[n], axy[m][n], 0, 0, 0);
                axy[m][n] = __builtin_amdgcn_mfma_f32_16x16x32_bf16(xh[m], pl[n], axy[m][n], 0, 0, 0);
                axy[m][n] = __builtin_amdgcn_mfma_f32_16x16x32_bf16(xl[m], ph[n], axy[m][n], 0, 0, 0);
                axa[m][n] = __builtin_amdgcn_mfma_f32_16x16x32_bf16(xh[m], ah[n], axa[m][n], 0, 0, 0);
                axa[m][n] = __builtin_amdgcn_mfma_f32_16x16x32_bf16(xh[m], al[n], axa[m][n], 0, 0, 0);
                axa[m][n] = __builtin_amdgcn_mfma_f32_16x16x32_bf16(xl[m], ah[n], axa[m][n], 0, 0, 0);
            }
    }

    // Epilogue. C/D mapping: col = lane&15, row = (lane>>4)*4 + reg.
    #pragma unroll
    for (int nf = 0; nf < 2; ++nf) {
        int n = n0 + wc * 32 + nf * 16 + (lane & 15);
        float p2 = p2s[n], pa = pas[n], an = ans[n], kk = ks[n];
        #pragma unroll
        for (int m = 0; m < 2; ++m) {
            #pragma unroll
            for (int rg = 0; rg < 4; ++rg) {
                int b = b0 + wr * 32 + m * 16 + (lane >> 4) * 4 + rg;
                float yy  = y2[b];
                float xy  = -axy[m][nf][rg];                 // (-P).X
                float xa  =  axa[m][nf][rg];
                float dnm = 1.f + 2.f * xy + p2 * yy + 1e-5f;
                float alpha = (1.f + 2.f * xy + yy) / dnm;   // coeff on (-P)
                float beta  = (1.f - p2) / dnm;              // coeff on X
                float num  = 2.f * (beta * xa - alpha * pa);
                float mob2 = alpha * alpha * p2 + beta * beta * yy
                           + 2.f * alpha * beta * xy;
                float den  = an * (1.f - mob2);
                out[(size_t)b * NN + n] = kk * asinhf(num / den);
            }
        }
    }
}

extern "C" void kernel_launch(void* const* d_in, const int* in_sizes, int n_in,
                              void* d_out, int out_size, void* d_ws, size_t ws_size,
                              hipStream_t stream) {
    const float* x      = (const float*)d_in[0];
    const float* a_vals = (const float*)d_in[1];
    const float* p_vals = (const float*)d_in[2];
    float* out = (float*)d_out;

    ushort* Xh = (ushort*)d_ws;                 // [BB][DD] bf16 hi (swizzled)
    ushort* Xl = Xh + (size_t)BB * DD;
    ushort* Ph = Xl + (size_t)BB * DD;          // [NN][DD]
    ushort* Pl = Ph + (size_t)NN * DD;
    ushort* Ah = Pl + (size_t)NN * DD;
    ushort* Al = Ah + (size_t)NN * DD;
    float*  y2  = (float*)(Al + (size_t)NN * DD);
    float*  p2s = y2 + BB;
    float*  pas = p2s + NN;
    float*  ans = pas + NN;
    float*  ks  = ans + NN;

    hipLaunchKernelGGL(hmlr_stage1, dim3(BB + NN), dim3(256), 0, stream,
                       x, a_vals, p_vals, Xh, Xl, Ph, Pl, Ah, Al,
                       y2, p2s, pas, ans, ks);
    hipLaunchKernelGGL(hmlr_stage2, dim3(NN / 64, BB / 64), dim3(256), 0, stream,
                       Xh, Xl, Ph, Pl, Ah, Al, y2, p2s, pas, ans, ks, out);
}